// Round 3
// baseline (810.030 us; speedup 1.0000x reference)
//
#include <hip/hip_runtime.h>

// ---------------------------------------------------------------------------
// SpatialGraphConv: N=32,C=32,V=400,L=64; 2 graphs, order 2, K=20, alpha=.05
// out = BN( sum_k M_k * (S_k x) ),  S in {I, A0^T, (A0^T)^2, A1^T, (A1^T)^2}
// MLP kept fp32 (logit noise must be <1e-3). Main GEMM path bf16 MFMA.
// R1: k_mlp3 lane=edge/wave=col-slice, weights on scalar pipe (100->? us).
// R2: k_prop rewritten: reg-transpose B staging (ds_write_b128, no b16
//     scatter -> was 15.3M bank conflicts = 26% of time), double-buffered
//     LDS + reg prefetch, 1 barrier/K-step (was 2). Occupancy grid-limited
//     (512 blocks = 2/CU) so latency hiding is in-block.
// ---------------------------------------------------------------------------

#define VDIM 400
#define VP   416            // v padded to multiple of 32
#define KV   (4*VP)         // 1664 : concat K dim over k=1..4
#define EROWS (5*VP)        // 2080 : e rows incl k=0
#define OL   2048           // 32 out-ch * 64 l
#define ALPHA_ 0.05f
#define BETA_  0.95f

typedef short  bf16x8 __attribute__((ext_vector_type(8)));
typedef float  f32x4  __attribute__((ext_vector_type(4)));

__device__ inline unsigned short f2bf(float x){
  unsigned int u = __float_as_uint(x);
  unsigned int r = (u + 0x7fffu + ((u >> 16) & 1u)) >> 16;
  return (unsigned short)r;
}
__device__ inline float bf2f(unsigned short u){
  return __uint_as_float(((unsigned int)u) << 16);
}

// ------------------------------------------------- edge MLP, fp32, R1 -------
// 64 edges/block, 256 threads = 4 waves. lane = edge, wave = column slice.
// Weights read via wave-uniform addresses -> scalar pipe (SMEM), not LDS.
__global__ __launch_bounds__(256) void k_mlp3(
    const float* __restrict__ adj,
    const float* __restrict__ w0, const float* __restrict__ b0,
    const float* __restrict__ w1, const float* __restrict__ b1,
    const float* __restrict__ w2, const float* __restrict__ b2,
    float* __restrict__ g)
{
  __shared__ __align__(16) float s_inT[64*68];   // [f][e], 17,408 B
  __shared__ __align__(16) float s_h1 [64*72];   // [e][n], 18,432 B
  __shared__ __align__(16) float s_red[4*64*2];  // 2,048 B
  const int tid  = threadIdx.x;
  const long ebase = (long)blockIdx.x * 64;
  const int wid  = __builtin_amdgcn_readfirstlane(tid >> 6);  // uniform wave id
  const int lane = tid & 63;                                  // = edge index

  // stage adj tile transposed: s_inT[f][e] = adj[ebase+e][f]
  #pragma unroll
  for (int i = 0; i < 4; ++i){
    const int idx = tid + i*256;
    const int row = idx >> 4, f4 = (idx & 15)*4;
    f32x4 v = *reinterpret_cast<const f32x4*>(&adj[(ebase + row)*64 + f4]);
    s_inT[(f4+0)*68 + row] = v.x;
    s_inT[(f4+1)*68 + row] = v.y;
    s_inT[(f4+2)*68 + row] = v.z;
    s_inT[(f4+3)*68 + row] = v.w;
  }
  __syncthreads();

  // ---- layer 0: h0[e = lane][n0 .. n0+31], n0 = wid*32 (K = 64)
  const int n0 = wid * 32;
  float h0[32];
  #pragma unroll
  for (int j = 0; j < 32; ++j) h0[j] = b0[n0 + j];           // uniform loads
  #pragma unroll 2
  for (int f = 0; f < 64; ++f){
    const float a = s_inT[f*68 + lane];                       // 1 ds_read_b32
    const float* __restrict__ wr = &w0[f*128 + n0];           // uniform -> SMEM
    #pragma unroll
    for (int j = 0; j < 32; ++j) h0[j] = fmaf(a, wr[j], h0[j]);
  }
  #pragma unroll
  for (int j = 0; j < 32; ++j) h0[j] = fmaxf(h0[j], 0.f);

  // ---- layer 1 partial: this wave's K-slice F = n0..n0+31, all 64 n-cols
  float p[64];
  #pragma unroll
  for (int nh = 0; nh < 2; ++nh){
    float acc1[32];
    #pragma unroll
    for (int j = 0; j < 32; ++j) acc1[j] = 0.f;
    #pragma unroll 2
    for (int f = 0; f < 32; ++f){
      const float hv = h0[f];
      const float* __restrict__ wr = &w1[(n0 + f)*64 + nh*32]; // uniform -> SMEM
      #pragma unroll
      for (int j = 0; j < 32; ++j) acc1[j] = fmaf(hv, wr[j], acc1[j]);
    }
    #pragma unroll
    for (int j = 0; j < 32; ++j) p[nh*32 + j] = acc1[j];
  }

  // ---- cross-wave accumulate into s_h1 (sequential phases, F-order 0..127)
  #pragma unroll
  for (int w = 0; w < 4; ++w){
    if (wid == w){
      if (w == 0){
        #pragma unroll
        for (int j = 0; j < 64; j += 4){
          f32x4 v = { p[j] + b1[j],   p[j+1] + b1[j+1],
                      p[j+2] + b1[j+2], p[j+3] + b1[j+3] };
          *reinterpret_cast<f32x4*>(&s_h1[lane*72 + j]) = v;
        }
      } else {
        #pragma unroll
        for (int j = 0; j < 64; j += 4){
          f32x4 v = *reinterpret_cast<f32x4*>(&s_h1[lane*72 + j]);
          v.x += p[j]; v.y += p[j+1]; v.z += p[j+2]; v.w += p[j+3];
          *reinterpret_cast<f32x4*>(&s_h1[lane*72 + j]) = v;
        }
      }
    }
    __syncthreads();
  }

  // ---- layer 2: g[e][gr] = relu(h1[e][:]) @ w2 + b2 ; wave handles 16 n's
  float q0 = 0.f, q1 = 0.f;
  #pragma unroll
  for (int j = 0; j < 16; ++j){
    const int n = wid*16 + j;
    const float hv = fmaxf(s_h1[lane*72 + n], 0.f);
    q0 = fmaf(hv, w2[n*2 + 0], q0);                           // uniform -> SMEM
    q1 = fmaf(hv, w2[n*2 + 1], q1);
  }
  s_red[(wid*64 + lane)*2 + 0] = q0;
  s_red[(wid*64 + lane)*2 + 1] = q1;
  __syncthreads();
  if (wid == 0){
    float r0 = b2[0], r1 = b2[1];
    #pragma unroll
    for (int w = 0; w < 4; ++w){
      r0 += s_red[(w*64 + lane)*2 + 0];
      r1 += s_red[(w*64 + lane)*2 + 1];
    }
    g[(ebase + lane)*2 + 0] = r0;
    g[(ebase + lane)*2 + 1] = r1;
  }
}

// ------------------------------------------- softmax + top-K + renorm + ^T --
// writes Bf[gr*2][w][v] = A_gr[v][w]   (1-hop transposed operator, fp32)
__global__ __launch_bounds__(256) void k_sparsify(
    const float* __restrict__ g, float* __restrict__ Bf)
{
  const int row = blockIdx.x, gr = blockIdx.y, tid = threadIdx.x;
  const int wid = tid >> 6, lane = tid & 63;
  __shared__ float s_v[4]; __shared__ int s_i[4];
  __shared__ float s_p[512];
  __shared__ int   s_sel[512];
  const int i0 = tid, i1 = tid + 256;
  float v0 = (i0 < VDIM) ? g[(row*VDIM + i0)*2 + gr] : -3.4e38f;
  float v1 = (i1 < VDIM) ? g[(row*VDIM + i1)*2 + gr] : -3.4e38f;

  float m = fmaxf(v0, v1);
  for (int off = 32; off > 0; off >>= 1) m = fmaxf(m, __shfl_down(m, off, 64));
  if (lane == 0) s_v[wid] = m;
  __syncthreads();
  const float rowmax = fmaxf(fmaxf(s_v[0], s_v[1]), fmaxf(s_v[2], s_v[3]));
  float p0 = (i0 < VDIM) ? expf(v0 - rowmax) : 0.f;
  float p1 = (i1 < VDIM) ? expf(v1 - rowmax) : 0.f;
  float zs = p0 + p1;
  for (int off = 32; off > 0; off >>= 1) zs += __shfl_down(zs, off, 64);
  __syncthreads();
  if (lane == 0) s_v[wid] = zs;
  __syncthreads();
  const float Z = s_v[0] + s_v[1] + s_v[2] + s_v[3];
  p0 /= Z; p1 /= Z;
  s_p[i0] = p0; s_p[i1] = p1;
  s_sel[i0] = (i0 < VDIM) ? 0 : 1;
  s_sel[i1] = (i1 < VDIM) ? 0 : 1;
  __syncthreads();

  float ssum = 0.f;
  for (int it = 0; it < 20; ++it){
    float cv = -1.f; int ci = 0x7fffffff;
    if (!s_sel[i0])              { cv = p0; ci = i0; }
    if (!s_sel[i1] && (p1 > cv)) { cv = p1; ci = i1; }
    for (int off = 32; off > 0; off >>= 1){
      float ov = __shfl_down(cv, off, 64); int oi = __shfl_down(ci, off, 64);
      if (ov > cv || (ov == cv && oi < ci)){ cv = ov; ci = oi; }
    }
    if (lane == 0){ s_v[wid] = cv; s_i[wid] = ci; }
    __syncthreads();
    float wv = s_v[0]; int wi_ = s_i[0];
    #pragma unroll
    for (int k = 1; k < 4; ++k){
      float ov = s_v[k]; int oi = s_i[k];
      if (ov > wv || (ov == wv && oi < wi_)){ wv = ov; wi_ = oi; }
    }
    ssum += wv;
    if (tid == (wi_ & 255)) s_sel[wi_] = 1;
    __syncthreads();
  }
  const float inv = 1.0f / (ssum + 1e-8f);
  float* B1 = Bf + (size_t)(gr*2) * (VDIM*VDIM);
  if (i0 < VDIM) B1[(size_t)i0*VDIM + row] = s_sel[i0] ? (s_p[i0]*inv) : 0.f;
  if (i1 < VDIM) B1[(size_t)i1*VDIM + row] = s_sel[i1] ? (s_p[i1]*inv) : 0.f;
}

// ------------------------------------------------ 2-hop: Bf[2g+1]=Bf[2g]^2 --
__global__ __launch_bounds__(256) void k_sq(float* __restrict__ Bf)
{
  const int gr = blockIdx.z;
  const float* S = Bf + (size_t)(2*gr)   * (VDIM*VDIM);
  float*       D = Bf + (size_t)(2*gr+1) * (VDIM*VDIM);
  const int tx = threadIdx.x & 15, ty = threadIdx.x >> 4;
  const int w = blockIdx.x*16 + ty, v = blockIdx.y*16 + tx;
  __shared__ float As[16][17], Bs[16][17];
  float acc = 0.f;
  for (int u0 = 0; u0 < VDIM; u0 += 16){
    As[ty][tx] = S[(size_t)w*VDIM + u0 + tx];
    Bs[ty][tx] = S[(size_t)(u0+ty)*VDIM + v];
    __syncthreads();
    #pragma unroll
    for (int u = 0; u < 16; ++u) acc += As[ty][u] * Bs[u][tx];
    __syncthreads();
  }
  D[(size_t)w*VDIM + v] = acc;
}

// ------------------- pack Bcat (bf16, padded) + build M'' + zero BN sums ---
__global__ __launch_bounds__(256) void k_pack(
    const float* __restrict__ Bf, const float* __restrict__ conv_w,
    unsigned short* __restrict__ Bcat, unsigned short* __restrict__ Mpp,
    float* __restrict__ bns)
{
  const int idx = blockIdx.x*256 + threadIdx.x;
  if (idx < 512*KV){
    const int w = idx / KV, col = idx % KV;
    const int k1 = col / VP, v = col % VP;
    float val = (w < VDIM && v < VDIM) ? Bf[(size_t)k1*(VDIM*VDIM) + (size_t)w*VDIM + v] : 0.f;
    Bcat[idx] = f2bf(val);
  }
  if (blockIdx.x == 0){
    const float a = ALPHA_, b = BETA_;
    for (int mIdx = threadIdx.x; mIdx < 160*32; mIdx += 256){
      const int rowm = mIdx >> 5, c = mIdx & 31;
      const int k = rowm / 32, o = rowm & 31;
      float W[5];
      #pragma unroll
      for (int j = 0; j < 5; ++j) W[j] = conv_w[o*160 + j*32 + c];
      float val;
      if      (k == 0) val = W[0] + a*(W[1]+W[2]+W[3]+W[4]);
      else if (k == 1) val = b*W[1] + a*b*W[2];
      else if (k == 2) val = b*b*W[2];
      else if (k == 3) val = b*W[3] + a*b*W[4];
      else             val = b*b*W[4];
      Mpp[rowm*32 + c] = f2bf(val);
    }
    if (threadIdx.x < 64) bns[threadIdx.x] = 0.f;
  }
}

// ----------------- e_k = M_k * relu(x), bf16, layout [n'][k*416+v][o*64+l] --
__global__ __launch_bounds__(640) void k_e(
    const float* __restrict__ x, const unsigned short* __restrict__ Mpp,
    unsigned short* __restrict__ e, int n0)
{
  const int v = blockIdx.x;
  const int n = n0 + blockIdx.y;
  const int tid = threadIdx.x;
  unsigned short* en = e + (size_t)blockIdx.y * EROWS * OL;
  if (v >= VDIM){
    for (int i = tid; i < 5*256; i += 640){
      const int k = i >> 8, off = (i & 255) * 8;
      *reinterpret_cast<uint4*>(&en[(size_t)(k*VP + v)*OL + off]) = make_uint4(0,0,0,0);
    }
    return;
  }
  __shared__ __align__(16) unsigned short s_xT[64*32];      // [l][c]
  __shared__ __align__(16) unsigned short s_out[10*16*64];  // per-wave [16][64]
  if (tid < 512){
    const int c = tid >> 4, l4 = (tid & 15) * 4;
    float4 xv = *reinterpret_cast<const float4*>(x + ((size_t)n*32 + c)*25600 + (size_t)v*64 + l4);
    s_xT[(l4+0)*32 + c] = f2bf(fmaxf(xv.x, 0.f));
    s_xT[(l4+1)*32 + c] = f2bf(fmaxf(xv.y, 0.f));
    s_xT[(l4+2)*32 + c] = f2bf(fmaxf(xv.z, 0.f));
    s_xT[(l4+3)*32 + c] = f2bf(fmaxf(xv.w, 0.f));
  }
  __syncthreads();
  const int wid = tid >> 6, lane = tid & 63;
  const int l15 = lane & 15, q = lane >> 4;
  const int m0 = wid * 16;
  bf16x8 afrag = *reinterpret_cast<const bf16x8*>(&Mpp[(m0 + l15)*32 + q*8]);
  const f32x4 zero = {0.f, 0.f, 0.f, 0.f};
  f32x4 acc[4];
  #pragma unroll
  for (int lt = 0; lt < 4; ++lt){
    bf16x8 bfrag = *reinterpret_cast<const bf16x8*>(&s_xT[(lt*16 + l15)*32 + q*8]);
    acc[lt] = __builtin_amdgcn_mfma_f32_16x16x32_bf16(afrag, bfrag, zero, 0, 0, 0);
  }
  unsigned short* so = &s_out[wid*1024];
  #pragma unroll
  for (int lt = 0; lt < 4; ++lt)
    #pragma unroll
    for (int r = 0; r < 4; ++r)
      so[(q*4 + r)*64 + lt*16 + l15] = f2bf(acc[lt][r]);
  const int k = wid >> 1, o0 = (wid & 1) * 16;
  const size_t gbase = (size_t)(k*VP + v)*OL + (size_t)o0*64;
  uint4 d0 = *reinterpret_cast<uint4*>(&so[lane*16]);
  uint4 d1 = *reinterpret_cast<uint4*>(&so[lane*16 + 8]);
  *reinterpret_cast<uint4*>(&en[gbase + lane*16])     = d0;
  *reinterpret_cast<uint4*>(&en[gbase + lane*16 + 8]) = d1;
}

// ------- main GEMM: out[w][(o,l)] = Bcat[w][kv] @ e[kv][(o,l)] + e0 + bias --
// R2: reg-transpose B staging (no b16 scatter), dbuf LDS, 1 barrier/K-step.
__global__ __launch_bounds__(256) void k_prop(
    const unsigned short* __restrict__ Bcat, const unsigned short* __restrict__ e,
    const float* __restrict__ conv_b, float* __restrict__ out,
    float* __restrict__ bns, int n0)
{
  const int mt = blockIdx.x, nt = blockIdx.y, np = blockIdx.z;
  const int tid = threadIdx.x;
  const int wid = tid >> 6, lane = tid & 63;
  const int l15 = lane & 15, q = lane >> 4;
  const int ww = wid & 1, wh = wid >> 1;
  const unsigned short* en = e + (size_t)np * EROWS * OL;
  __shared__ __align__(16) unsigned short s_a[2][128*40];  // [m][32k] pad 40
  __shared__ __align__(16) unsigned short s_b[2][128*40];  // [n][32k] pad 40
  const f32x4 zero = {0.f, 0.f, 0.f, 0.f};
  f32x4 acc[4][4];
  #pragma unroll
  for (int mi = 0; mi < 4; ++mi)
    #pragma unroll
    for (int ni = 0; ni < 4; ++ni) acc[mi][ni] = zero;
  const int w_base = mt*128, ol0 = nt*128;

  // staging thread maps (fixed per thread)
  const int brg = tid >> 6;          // B: k-row group, r0 = brg*8
  const int bnb = tid & 63;          // B: col pair,   n0 = bnb*2

  uint4        aR[2];
  unsigned int bR[8];

  // global -> regs for K-step kk (A: 2x dwordx4; B: 8x dword, coalesced)
  auto LOADG = [&](int kk){
    #pragma unroll
    for (int i = 0; i < 2; ++i){
      const int idx = tid + i*256;
      const int m = idx >> 2, seg = idx & 3;
      aR[i] = *reinterpret_cast<const uint4*>(&Bcat[(size_t)(w_base + m)*KV + kk + seg*8]);
    }
    #pragma unroll
    for (int i = 0; i < 8; ++i)
      bR[i] = *reinterpret_cast<const unsigned int*>(
                 &en[(size_t)(VP + kk + brg*8 + i)*OL + ol0 + bnb*2]);
  };
  // regs -> LDS buf (A: straight; B: 4x4-ish in-reg transpose, b128 writes)
  auto STORES = [&](int buf){
    #pragma unroll
    for (int i = 0; i < 2; ++i){
      const int idx = tid + i*256;
      const int m = idx >> 2, seg = idx & 3;
      *reinterpret_cast<uint4*>(&s_a[buf][m*40 + seg*8]) = aR[i];
    }
    uint4 t;
    t.x = (bR[0] & 0xffffu) | (bR[1] << 16);
    t.y = (bR[2] & 0xffffu) | (bR[3] << 16);
    t.z = (bR[4] & 0xffffu) | (bR[5] << 16);
    t.w = (bR[6] & 0xffffu) | (bR[7] << 16);
    *reinterpret_cast<uint4*>(&s_b[buf][(bnb*2 + 0)*40 + brg*8]) = t;
    t.x = (bR[0] >> 16) | (bR[1] & 0xffff0000u);
    t.y = (bR[2] >> 16) | (bR[3] & 0xffff0000u);
    t.z = (bR[4] >> 16) | (bR[5] & 0xffff0000u);
    t.w = (bR[6] >> 16) | (bR[7] & 0xffff0000u);
    *reinterpret_cast<uint4*>(&s_b[buf][(bnb*2 + 1)*40 + brg*8]) = t;
  };

  LOADG(0);
  STORES(0);
  __syncthreads();
  int cur = 0;

  for (int kk = 0; kk < KV; kk += 32){
    const bool more = (kk + 32 < KV);
    if (more) LOADG(kk + 32);          // issue early: hides under MFMA below

    bf16x8 af[4], bfr[4];
    #pragma unroll
    for (int mi = 0; mi < 4; ++mi){
      const int m = ww*64 + mi*16 + l15;
      af[mi] = *reinterpret_cast<const bf16x8*>(&s_a[cur][m*40 + q*8]);
    }
    #pragma unroll
    for (int ni = 0; ni < 4; ++ni){
      const int nn = wh*64 + ni*16 + l15;
      bfr[ni] = *reinterpret_cast<const bf16x8*>(&s_b[cur][nn*40 + q*8]);
    }
    #pragma unroll
    for (int mi = 0; mi < 4; ++mi)
      #pragma unroll
      for (int ni = 0; ni < 4; ++ni)
        acc[mi][ni] = __builtin_amdgcn_mfma_f32_16x16x32_bf16(af[mi], bfr[ni], acc[mi][ni], 0, 0, 0);

    if (more) STORES(cur ^ 1);         // waits vmcnt as needed (compiler)
    __syncthreads();                   // single barrier per K-step
    cur ^= 1;
  }

  const int n_g = n0 + np;
  const int o = (ol0 >> 6) + wh;          // each wave maps to exactly one out channel
  const float cb = conv_b[o];
  float bsum = 0.f, bsq = 0.f;
  #pragma unroll
  for (int mi = 0; mi < 4; ++mi){
    #pragma unroll
    for (int ni = 0; ni < 4; ++ni){
      const int nloc = wh*64 + ni*16 + l15;
      const int ol = ol0 + nloc;
      const int l = ol & 63;
      #pragma unroll
      for (int r = 0; r < 4; ++r){
        const int w = w_base + ww*64 + mi*16 + q*4 + r;
        if (w < VDIM){
          float val = acc[mi][ni][r] + bf2f(en[(size_t)w*OL + ol]) + cb;
          out[(((size_t)n_g*32 + o)*VDIM + w)*64 + l] = val;
          bsum += val; bsq += val*val;
        }
      }
    }
  }
  for (int off = 32; off > 0; off >>= 1){
    bsum += __shfl_down(bsum, off, 64);
    bsq  += __shfl_down(bsq,  off, 64);
  }
  if (lane == 0){
    atomicAdd(&bns[o], bsum);
    atomicAdd(&bns[32 + o], bsq);
  }
}

// --------------------------------------------------- batchnorm (in-place) --
__global__ __launch_bounds__(256) void k_bnapply(
    float* __restrict__ out, const float* __restrict__ bns,
    const float* __restrict__ gamma, const float* __restrict__ beta, int total4)
{
  const int idx = blockIdx.x*256 + threadIdx.x;
  if (idx >= total4) return;
  const int o = (int)(((long)idx*4 / 25600) & 31);
  const float invM = 1.f / 819200.f;
  const float mean = bns[o] * invM;
  const float var  = bns[32+o] * invM - mean*mean;
  const float inv  = 1.0f / sqrtf(var + 1e-5f);
  const float sc = inv * gamma[o];
  const float sh = beta[o] - mean * sc;
  float4 v = reinterpret_cast<float4*>(out)[idx];
  v.x = v.x*sc + sh; v.y = v.y*sc + sh; v.z = v.z*sc + sh; v.w = v.w*sc + sh;
  reinterpret_cast<float4*>(out)[idx] = v;
}

// ---------------------------------------------------------------------------
extern "C" void kernel_launch(void* const* d_in, const int* in_sizes, int n_in,
                              void* d_out, int out_size, void* d_ws, size_t ws_size,
                              hipStream_t stream)
{
  const float* x      = (const float*)d_in[0];
  const float* adj    = (const float*)d_in[1];
  const float* w0     = (const float*)d_in[2];
  const float* b0     = (const float*)d_in[3];
  const float* w1     = (const float*)d_in[4];
  const float* b1     = (const float*)d_in[5];
  const float* w2     = (const float*)d_in[6];
  const float* b2     = (const float*)d_in[7];
  const float* conv_w = (const float*)d_in[8];
  const float* conv_b = (const float*)d_in[9];
  const float* gamma  = (const float*)d_in[10];
  const float* beta   = (const float*)d_in[11];
  float* out = (float*)d_out;

  char* ws = (char*)d_ws;
  size_t off = 0;
  auto alloc = [&](size_t bytes) -> void* {
    void* p = ws + off;
    off = (off + bytes + 255) & ~(size_t)255;
    return p;
  };
  float*          g_   = (float*)         alloc((size_t)VDIM*VDIM*2*4);
  float*          Bf   = (float*)         alloc((size_t)4*VDIM*VDIM*4);
  unsigned short* Bcat = (unsigned short*)alloc((size_t)512*KV*2);
  unsigned short* Mpp  = (unsigned short*)alloc((size_t)160*32*2);
  float*          bns  = (float*)         alloc((size_t)64*4);
  const size_t per_n = (size_t)EROWS * OL * 2;
  size_t avail = (ws_size > off) ? (ws_size - off) : 0;
  int NC = (int)(avail / per_n);
  if (NC > 8) NC = 8;
  if (NC < 1) NC = 1;
  while (32 % NC) NC--;
  unsigned short* ebuf = (unsigned short*)(ws + off);

  k_mlp3<<<2500, 256, 0, stream>>>(adj, w0, b0, w1, b1, w2, b2, g_);
  k_sparsify<<<dim3(VDIM, 2), 256, 0, stream>>>(g_, Bf);
  k_sq<<<dim3(25, 25, 2), 256, 0, stream>>>(Bf);
  k_pack<<<(512*KV + 255)/256, 256, 0, stream>>>(Bf, conv_w, Bcat, Mpp, bns);
  for (int n0 = 0; n0 < 32; n0 += NC){
    k_e<<<dim3(VP, NC), 640, 0, stream>>>(x, Mpp, ebuf, n0);
    k_prop<<<dim3(4, 16, NC), 256, 0, stream>>>(Bcat, ebuf, conv_b, out, bns, n0);
  }
  k_bnapply<<<(26214400/4 + 255)/256, 256, 0, stream>>>(out, bns, gamma, beta, 26214400/4);
}

// Round 4
// 725.105 us; speedup vs baseline: 1.1171x; 1.1171x over previous
//
#include <hip/hip_runtime.h>

// ---------------------------------------------------------------------------
// SpatialGraphConv: N=32,C=32,V=400,L=64; 2 graphs, order 2, K=20, alpha=.05
// out = BN( sum_k M_k * (S_k x) ),  S in {I, A0^T, (A0^T)^2, A1^T, (A1^T)^2}
// MLP kept fp32 (logit noise must be <1e-3). Main GEMM path bf16 MFMA.
// R1: k_mlp3 lane=edge/wave=col-slice, weights on scalar pipe (100us -> off top5).
// R2: k_prop reg-transpose staging FAILED (95->102us): narrow B loads cost
//     more than the 15.3M->6.8M conflict fix saved. REVERTED to R1 k_prop.
// R3: k_prop is latency-bound (Mfma 11%, VALU 18%, HBM 19%, occ 18% = grid
//     limited at 2 blocks/CU). NC cap 8->32: one 2048-block launch -> 6
//     blocks/CU (VGPR-capped), 3x TLP. ws-adaptive, falls back if small.
// ---------------------------------------------------------------------------

#define VDIM 400
#define VP   416            // v padded to multiple of 32
#define KV   (4*VP)         // 1664 : concat K dim over k=1..4
#define EROWS (5*VP)        // 2080 : e rows incl k=0
#define OL   2048           // 32 out-ch * 64 l
#define ALPHA_ 0.05f
#define BETA_  0.95f

typedef short  bf16x8 __attribute__((ext_vector_type(8)));
typedef float  f32x4  __attribute__((ext_vector_type(4)));

__device__ inline unsigned short f2bf(float x){
  unsigned int u = __float_as_uint(x);
  unsigned int r = (u + 0x7fffu + ((u >> 16) & 1u)) >> 16;
  return (unsigned short)r;
}
__device__ inline float bf2f(unsigned short u){
  return __uint_as_float(((unsigned int)u) << 16);
}

// ------------------------------------------------- edge MLP, fp32, R1 -------
__global__ __launch_bounds__(256) void k_mlp3(
    const float* __restrict__ adj,
    const float* __restrict__ w0, const float* __restrict__ b0,
    const float* __restrict__ w1, const float* __restrict__ b1,
    const float* __restrict__ w2, const float* __restrict__ b2,
    float* __restrict__ g)
{
  __shared__ __align__(16) float s_inT[64*68];   // [f][e], 17,408 B
  __shared__ __align__(16) float s_h1 [64*72];   // [e][n], 18,432 B
  __shared__ __align__(16) float s_red[4*64*2];  // 2,048 B
  const int tid  = threadIdx.x;
  const long ebase = (long)blockIdx.x * 64;
  const int wid  = __builtin_amdgcn_readfirstlane(tid >> 6);  // uniform wave id
  const int lane = tid & 63;                                  // = edge index

  // stage adj tile transposed: s_inT[f][e] = adj[ebase+e][f]
  #pragma unroll
  for (int i = 0; i < 4; ++i){
    const int idx = tid + i*256;
    const int row = idx >> 4, f4 = (idx & 15)*4;
    f32x4 v = *reinterpret_cast<const f32x4*>(&adj[(ebase + row)*64 + f4]);
    s_inT[(f4+0)*68 + row] = v.x;
    s_inT[(f4+1)*68 + row] = v.y;
    s_inT[(f4+2)*68 + row] = v.z;
    s_inT[(f4+3)*68 + row] = v.w;
  }
  __syncthreads();

  // ---- layer 0: h0[e = lane][n0 .. n0+31], n0 = wid*32 (K = 64)
  const int n0 = wid * 32;
  float h0[32];
  #pragma unroll
  for (int j = 0; j < 32; ++j) h0[j] = b0[n0 + j];           // uniform loads
  #pragma unroll 2
  for (int f = 0; f < 64; ++f){
    const float a = s_inT[f*68 + lane];                       // 1 ds_read_b32
    const float* __restrict__ wr = &w0[f*128 + n0];           // uniform -> SMEM
    #pragma unroll
    for (int j = 0; j < 32; ++j) h0[j] = fmaf(a, wr[j], h0[j]);
  }
  #pragma unroll
  for (int j = 0; j < 32; ++j) h0[j] = fmaxf(h0[j], 0.f);

  // ---- layer 1 partial: this wave's K-slice F = n0..n0+31, all 64 n-cols
  float p[64];
  #pragma unroll
  for (int nh = 0; nh < 2; ++nh){
    float acc1[32];
    #pragma unroll
    for (int j = 0; j < 32; ++j) acc1[j] = 0.f;
    #pragma unroll 2
    for (int f = 0; f < 32; ++f){
      const float hv = h0[f];
      const float* __restrict__ wr = &w1[(n0 + f)*64 + nh*32]; // uniform -> SMEM
      #pragma unroll
      for (int j = 0; j < 32; ++j) acc1[j] = fmaf(hv, wr[j], acc1[j]);
    }
    #pragma unroll
    for (int j = 0; j < 32; ++j) p[nh*32 + j] = acc1[j];
  }

  // ---- cross-wave accumulate into s_h1 (sequential phases, F-order 0..127)
  #pragma unroll
  for (int w = 0; w < 4; ++w){
    if (wid == w){
      if (w == 0){
        #pragma unroll
        for (int j = 0; j < 64; j += 4){
          f32x4 v = { p[j] + b1[j],   p[j+1] + b1[j+1],
                      p[j+2] + b1[j+2], p[j+3] + b1[j+3] };
          *reinterpret_cast<f32x4*>(&s_h1[lane*72 + j]) = v;
        }
      } else {
        #pragma unroll
        for (int j = 0; j < 64; j += 4){
          f32x4 v = *reinterpret_cast<f32x4*>(&s_h1[lane*72 + j]);
          v.x += p[j]; v.y += p[j+1]; v.z += p[j+2]; v.w += p[j+3];
          *reinterpret_cast<f32x4*>(&s_h1[lane*72 + j]) = v;
        }
      }
    }
    __syncthreads();
  }

  // ---- layer 2: g[e][gr] = relu(h1[e][:]) @ w2 + b2 ; wave handles 16 n's
  float q0 = 0.f, q1 = 0.f;
  #pragma unroll
  for (int j = 0; j < 16; ++j){
    const int n = wid*16 + j;
    const float hv = fmaxf(s_h1[lane*72 + n], 0.f);
    q0 = fmaf(hv, w2[n*2 + 0], q0);                           // uniform -> SMEM
    q1 = fmaf(hv, w2[n*2 + 1], q1);
  }
  s_red[(wid*64 + lane)*2 + 0] = q0;
  s_red[(wid*64 + lane)*2 + 1] = q1;
  __syncthreads();
  if (wid == 0){
    float r0 = b2[0], r1 = b2[1];
    #pragma unroll
    for (int w = 0; w < 4; ++w){
      r0 += s_red[(w*64 + lane)*2 + 0];
      r1 += s_red[(w*64 + lane)*2 + 1];
    }
    g[(ebase + lane)*2 + 0] = r0;
    g[(ebase + lane)*2 + 1] = r1;
  }
}

// ------------------------------------------- softmax + top-K + renorm + ^T --
// writes Bf[gr*2][w][v] = A_gr[v][w]   (1-hop transposed operator, fp32)
__global__ __launch_bounds__(256) void k_sparsify(
    const float* __restrict__ g, float* __restrict__ Bf)
{
  const int row = blockIdx.x, gr = blockIdx.y, tid = threadIdx.x;
  const int wid = tid >> 6, lane = tid & 63;
  __shared__ float s_v[4]; __shared__ int s_i[4];
  __shared__ float s_p[512];
  __shared__ int   s_sel[512];
  const int i0 = tid, i1 = tid + 256;
  float v0 = (i0 < VDIM) ? g[(row*VDIM + i0)*2 + gr] : -3.4e38f;
  float v1 = (i1 < VDIM) ? g[(row*VDIM + i1)*2 + gr] : -3.4e38f;

  float m = fmaxf(v0, v1);
  for (int off = 32; off > 0; off >>= 1) m = fmaxf(m, __shfl_down(m, off, 64));
  if (lane == 0) s_v[wid] = m;
  __syncthreads();
  const float rowmax = fmaxf(fmaxf(s_v[0], s_v[1]), fmaxf(s_v[2], s_v[3]));
  float p0 = (i0 < VDIM) ? expf(v0 - rowmax) : 0.f;
  float p1 = (i1 < VDIM) ? expf(v1 - rowmax) : 0.f;
  float zs = p0 + p1;
  for (int off = 32; off > 0; off >>= 1) zs += __shfl_down(zs, off, 64);
  __syncthreads();
  if (lane == 0) s_v[wid] = zs;
  __syncthreads();
  const float Z = s_v[0] + s_v[1] + s_v[2] + s_v[3];
  p0 /= Z; p1 /= Z;
  s_p[i0] = p0; s_p[i1] = p1;
  s_sel[i0] = (i0 < VDIM) ? 0 : 1;
  s_sel[i1] = (i1 < VDIM) ? 0 : 1;
  __syncthreads();

  float ssum = 0.f;
  for (int it = 0; it < 20; ++it){
    float cv = -1.f; int ci = 0x7fffffff;
    if (!s_sel[i0])              { cv = p0; ci = i0; }
    if (!s_sel[i1] && (p1 > cv)) { cv = p1; ci = i1; }
    for (int off = 32; off > 0; off >>= 1){
      float ov = __shfl_down(cv, off, 64); int oi = __shfl_down(ci, off, 64);
      if (ov > cv || (ov == cv && oi < ci)){ cv = ov; ci = oi; }
    }
    if (lane == 0){ s_v[wid] = cv; s_i[wid] = ci; }
    __syncthreads();
    float wv = s_v[0]; int wi_ = s_i[0];
    #pragma unroll
    for (int k = 1; k < 4; ++k){
      float ov = s_v[k]; int oi = s_i[k];
      if (ov > wv || (ov == wv && oi < wi_)){ wv = ov; wi_ = oi; }
    }
    ssum += wv;
    if (tid == (wi_ & 255)) s_sel[wi_] = 1;
    __syncthreads();
  }
  const float inv = 1.0f / (ssum + 1e-8f);
  float* B1 = Bf + (size_t)(gr*2) * (VDIM*VDIM);
  if (i0 < VDIM) B1[(size_t)i0*VDIM + row] = s_sel[i0] ? (s_p[i0]*inv) : 0.f;
  if (i1 < VDIM) B1[(size_t)i1*VDIM + row] = s_sel[i1] ? (s_p[i1]*inv) : 0.f;
}

// ------------------------------------------------ 2-hop: Bf[2g+1]=Bf[2g]^2 --
__global__ __launch_bounds__(256) void k_sq(float* __restrict__ Bf)
{
  const int gr = blockIdx.z;
  const float* S = Bf + (size_t)(2*gr)   * (VDIM*VDIM);
  float*       D = Bf + (size_t)(2*gr+1) * (VDIM*VDIM);
  const int tx = threadIdx.x & 15, ty = threadIdx.x >> 4;
  const int w = blockIdx.x*16 + ty, v = blockIdx.y*16 + tx;
  __shared__ float As[16][17], Bs[16][17];
  float acc = 0.f;
  for (int u0 = 0; u0 < VDIM; u0 += 16){
    As[ty][tx] = S[(size_t)w*VDIM + u0 + tx];
    Bs[ty][tx] = S[(size_t)(u0+ty)*VDIM + v];
    __syncthreads();
    #pragma unroll
    for (int u = 0; u < 16; ++u) acc += As[ty][u] * Bs[u][tx];
    __syncthreads();
  }
  D[(size_t)w*VDIM + v] = acc;
}

// ------------------- pack Bcat (bf16, padded) + build M'' + zero BN sums ---
__global__ __launch_bounds__(256) void k_pack(
    const float* __restrict__ Bf, const float* __restrict__ conv_w,
    unsigned short* __restrict__ Bcat, unsigned short* __restrict__ Mpp,
    float* __restrict__ bns)
{
  const int idx = blockIdx.x*256 + threadIdx.x;
  if (idx < 512*KV){
    const int w = idx / KV, col = idx % KV;
    const int k1 = col / VP, v = col % VP;
    float val = (w < VDIM && v < VDIM) ? Bf[(size_t)k1*(VDIM*VDIM) + (size_t)w*VDIM + v] : 0.f;
    Bcat[idx] = f2bf(val);
  }
  if (blockIdx.x == 0){
    const float a = ALPHA_, b = BETA_;
    for (int mIdx = threadIdx.x; mIdx < 160*32; mIdx += 256){
      const int rowm = mIdx >> 5, c = mIdx & 31;
      const int k = rowm / 32, o = rowm & 31;
      float W[5];
      #pragma unroll
      for (int j = 0; j < 5; ++j) W[j] = conv_w[o*160 + j*32 + c];
      float val;
      if      (k == 0) val = W[0] + a*(W[1]+W[2]+W[3]+W[4]);
      else if (k == 1) val = b*W[1] + a*b*W[2];
      else if (k == 2) val = b*b*W[2];
      else if (k == 3) val = b*W[3] + a*b*W[4];
      else             val = b*b*W[4];
      Mpp[rowm*32 + c] = f2bf(val);
    }
    if (threadIdx.x < 64) bns[threadIdx.x] = 0.f;
  }
}

// ----------------- e_k = M_k * relu(x), bf16, layout [n'][k*416+v][o*64+l] --
__global__ __launch_bounds__(640) void k_e(
    const float* __restrict__ x, const unsigned short* __restrict__ Mpp,
    unsigned short* __restrict__ e, int n0)
{
  const int v = blockIdx.x;
  const int n = n0 + blockIdx.y;
  const int tid = threadIdx.x;
  unsigned short* en = e + (size_t)blockIdx.y * EROWS * OL;
  if (v >= VDIM){
    for (int i = tid; i < 5*256; i += 640){
      const int k = i >> 8, off = (i & 255) * 8;
      *reinterpret_cast<uint4*>(&en[(size_t)(k*VP + v)*OL + off]) = make_uint4(0,0,0,0);
    }
    return;
  }
  __shared__ __align__(16) unsigned short s_xT[64*32];      // [l][c]
  __shared__ __align__(16) unsigned short s_out[10*16*64];  // per-wave [16][64]
  if (tid < 512){
    const int c = tid >> 4, l4 = (tid & 15) * 4;
    float4 xv = *reinterpret_cast<const float4*>(x + ((size_t)n*32 + c)*25600 + (size_t)v*64 + l4);
    s_xT[(l4+0)*32 + c] = f2bf(fmaxf(xv.x, 0.f));
    s_xT[(l4+1)*32 + c] = f2bf(fmaxf(xv.y, 0.f));
    s_xT[(l4+2)*32 + c] = f2bf(fmaxf(xv.z, 0.f));
    s_xT[(l4+3)*32 + c] = f2bf(fmaxf(xv.w, 0.f));
  }
  __syncthreads();
  const int wid = tid >> 6, lane = tid & 63;
  const int l15 = lane & 15, q = lane >> 4;
  const int m0 = wid * 16;
  bf16x8 afrag = *reinterpret_cast<const bf16x8*>(&Mpp[(m0 + l15)*32 + q*8]);
  const f32x4 zero = {0.f, 0.f, 0.f, 0.f};
  f32x4 acc[4];
  #pragma unroll
  for (int lt = 0; lt < 4; ++lt){
    bf16x8 bfrag = *reinterpret_cast<const bf16x8*>(&s_xT[(lt*16 + l15)*32 + q*8]);
    acc[lt] = __builtin_amdgcn_mfma_f32_16x16x32_bf16(afrag, bfrag, zero, 0, 0, 0);
  }
  unsigned short* so = &s_out[wid*1024];
  #pragma unroll
  for (int lt = 0; lt < 4; ++lt)
    #pragma unroll
    for (int r = 0; r < 4; ++r)
      so[(q*4 + r)*64 + lt*16 + l15] = f2bf(acc[lt][r]);
  const int k = wid >> 1, o0 = (wid & 1) * 16;
  const size_t gbase = (size_t)(k*VP + v)*OL + (size_t)o0*64;
  uint4 d0 = *reinterpret_cast<uint4*>(&so[lane*16]);
  uint4 d1 = *reinterpret_cast<uint4*>(&so[lane*16 + 8]);
  *reinterpret_cast<uint4*>(&en[gbase + lane*16])     = d0;
  *reinterpret_cast<uint4*>(&en[gbase + lane*16 + 8]) = d1;
}

// ------- main GEMM: out[w][(o,l)] = Bcat[w][kv] @ e[kv][(o,l)] + e0 + bias --
// (R1 version: verified fastest staging; occupancy now comes from the grid.)
__global__ __launch_bounds__(256) void k_prop(
    const unsigned short* __restrict__ Bcat, const unsigned short* __restrict__ e,
    const float* __restrict__ conv_b, float* __restrict__ out,
    float* __restrict__ bns, int n0)
{
  const int mt = blockIdx.x, nt = blockIdx.y, np = blockIdx.z;
  const int tid = threadIdx.x;
  const int wid = tid >> 6, lane = tid & 63;
  const int l15 = lane & 15, q = lane >> 4;
  const int ww = wid & 1, wh = wid >> 1;
  const unsigned short* en = e + (size_t)np * EROWS * OL;
  __shared__ __align__(16) unsigned short s_a[128*40];  // padded rows
  __shared__ __align__(16) unsigned short s_b[128*32];  // xor-swizzled [n][k]
  const f32x4 zero = {0.f, 0.f, 0.f, 0.f};
  f32x4 acc[4][4];
  #pragma unroll
  for (int mi = 0; mi < 4; ++mi)
    #pragma unroll
    for (int ni = 0; ni < 4; ++ni) acc[mi][ni] = zero;
  const int w_base = mt*128, ol0 = nt*128;

  for (int kk = 0; kk < KV; kk += 32){
    #pragma unroll
    for (int i = 0; i < 2; ++i){
      const int idx = tid + i*256;
      const int m = idx >> 2, seg = idx & 3;
      uint4 d = *reinterpret_cast<const uint4*>(&Bcat[(size_t)(w_base + m)*KV + kk + seg*8]);
      *reinterpret_cast<uint4*>(&s_a[m*40 + seg*8]) = d;
    }
    #pragma unroll
    for (int i = 0; i < 2; ++i){
      const int idx = tid + i*256;
      const int r = idx >> 4, seg = idx & 15;
      union { uint4 u; unsigned short s[8]; } d;
      d.u = *reinterpret_cast<const uint4*>(&en[(size_t)(VP + kk + r)*OL + ol0 + seg*8]);
      const int kb = r >> 3, kin = r & 7;
      #pragma unroll
      for (int t = 0; t < 8; ++t){
        const int nn = seg*8 + t;
        s_b[nn*32 + ((kb ^ ((nn >> 3) & 3)) << 3) + kin] = d.s[t];
      }
    }
    __syncthreads();
    bf16x8 af[4], bfr[4];
    #pragma unroll
    for (int mi = 0; mi < 4; ++mi){
      const int m = ww*64 + mi*16 + l15;
      af[mi] = *reinterpret_cast<const bf16x8*>(&s_a[m*40 + q*8]);
    }
    #pragma unroll
    for (int ni = 0; ni < 4; ++ni){
      const int nn = wh*64 + ni*16 + l15;
      bfr[ni] = *reinterpret_cast<const bf16x8*>(&s_b[nn*32 + ((q ^ ((nn >> 3) & 3)) << 3)]);
    }
    #pragma unroll
    for (int mi = 0; mi < 4; ++mi)
      #pragma unroll
      for (int ni = 0; ni < 4; ++ni)
        acc[mi][ni] = __builtin_amdgcn_mfma_f32_16x16x32_bf16(af[mi], bfr[ni], acc[mi][ni], 0, 0, 0);
    __syncthreads();
  }

  const int n_g = n0 + np;
  const int o = (ol0 >> 6) + wh;          // each wave maps to exactly one out channel
  const float cb = conv_b[o];
  float bsum = 0.f, bsq = 0.f;
  #pragma unroll
  for (int mi = 0; mi < 4; ++mi){
    #pragma unroll
    for (int ni = 0; ni < 4; ++ni){
      const int nloc = wh*64 + ni*16 + l15;
      const int ol = ol0 + nloc;
      const int l = ol & 63;
      #pragma unroll
      for (int r = 0; r < 4; ++r){
        const int w = w_base + ww*64 + mi*16 + q*4 + r;
        if (w < VDIM){
          float val = acc[mi][ni][r] + bf2f(en[(size_t)w*OL + ol]) + cb;
          out[(((size_t)n_g*32 + o)*VDIM + w)*64 + l] = val;
          bsum += val; bsq += val*val;
        }
      }
    }
  }
  for (int off = 32; off > 0; off >>= 1){
    bsum += __shfl_down(bsum, off, 64);
    bsq  += __shfl_down(bsq,  off, 64);
  }
  if (lane == 0){
    atomicAdd(&bns[o], bsum);
    atomicAdd(&bns[32 + o], bsq);
  }
}

// --------------------------------------------------- batchnorm (in-place) --
__global__ __launch_bounds__(256) void k_bnapply(
    float* __restrict__ out, const float* __restrict__ bns,
    const float* __restrict__ gamma, const float* __restrict__ beta, int total4)
{
  const int idx = blockIdx.x*256 + threadIdx.x;
  if (idx >= total4) return;
  const int o = (int)(((long)idx*4 / 25600) & 31);
  const float invM = 1.f / 819200.f;
  const float mean = bns[o] * invM;
  const float var  = bns[32+o] * invM - mean*mean;
  const float inv  = 1.0f / sqrtf(var + 1e-5f);
  const float sc = inv * gamma[o];
  const float sh = beta[o] - mean * sc;
  float4 v = reinterpret_cast<float4*>(out)[idx];
  v.x = v.x*sc + sh; v.y = v.y*sc + sh; v.z = v.z*sc + sh; v.w = v.w*sc + sh;
  reinterpret_cast<float4*>(out)[idx] = v;
}

// ---------------------------------------------------------------------------
extern "C" void kernel_launch(void* const* d_in, const int* in_sizes, int n_in,
                              void* d_out, int out_size, void* d_ws, size_t ws_size,
                              hipStream_t stream)
{
  const float* x      = (const float*)d_in[0];
  const float* adj    = (const float*)d_in[1];
  const float* w0     = (const float*)d_in[2];
  const float* b0     = (const float*)d_in[3];
  const float* w1     = (const float*)d_in[4];
  const float* b1     = (const float*)d_in[5];
  const float* w2     = (const float*)d_in[6];
  const float* b2     = (const float*)d_in[7];
  const float* conv_w = (const float*)d_in[8];
  const float* conv_b = (const float*)d_in[9];
  const float* gamma  = (const float*)d_in[10];
  const float* beta   = (const float*)d_in[11];
  float* out = (float*)d_out;

  char* ws = (char*)d_ws;
  size_t off = 0;
  auto alloc = [&](size_t bytes) -> void* {
    void* p = ws + off;
    off = (off + bytes + 255) & ~(size_t)255;
    return p;
  };
  float*          g_   = (float*)         alloc((size_t)VDIM*VDIM*2*4);
  float*          Bf   = (float*)         alloc((size_t)4*VDIM*VDIM*4);
  unsigned short* Bcat = (unsigned short*)alloc((size_t)512*KV*2);
  unsigned short* Mpp  = (unsigned short*)alloc((size_t)160*32*2);
  float*          bns  = (float*)         alloc((size_t)64*4);
  const size_t per_n = (size_t)EROWS * OL * 2;
  size_t avail = (ws_size > off) ? (ws_size - off) : 0;
  int NC = (int)(avail / per_n);
  if (NC > 32) NC = 32;           // R3: raised cap (was 8). 32 -> one k_prop
  if (NC < 1) NC = 1;             // launch of 2048 blocks = 6 blocks/CU.
  while (32 % NC) NC--;
  unsigned short* ebuf = (unsigned short*)(ws + off);

  k_mlp3<<<2500, 256, 0, stream>>>(adj, w0, b0, w1, b1, w2, b2, g_);
  k_sparsify<<<dim3(VDIM, 2), 256, 0, stream>>>(g_, Bf);
  k_sq<<<dim3(25, 25, 2), 256, 0, stream>>>(Bf);
  k_pack<<<(512*KV + 255)/256, 256, 0, stream>>>(Bf, conv_w, Bcat, Mpp, bns);
  for (int n0 = 0; n0 < 32; n0 += NC){
    k_e<<<dim3(VP, NC), 640, 0, stream>>>(x, Mpp, ebuf, n0);
    k_prop<<<dim3(4, 16, NC), 256, 0, stream>>>(Bcat, ebuf, conv_b, out, bns, n0);
  }
  k_bnapply<<<(26214400/4 + 255)/256, 256, 0, stream>>>(out, bns, gamma, beta, 26214400/4);
}

// Round 5
// 702.000 us; speedup vs baseline: 1.1539x; 1.0329x over previous
//
#include <hip/hip_runtime.h>

// ---------------------------------------------------------------------------
// SpatialGraphConv: N=32,C=32,V=400,L=64; 2 graphs, order 2, K=20, alpha=.05
// out = BN( sum_k M_k * (S_k x) ),  S in {I, A0^T, (A0^T)^2, A1^T, (A1^T)^2}
// MLP kept fp32 (logit noise must be <1e-3). Main GEMM path bf16 MFMA.
// R1: k_mlp3 lane=edge/wave=col-slice, weights on scalar pipe.
// R2: k_prop reg-transpose w/ narrow loads FAILED (95->102). Reverted.
// R3: NC cap 8->32: one k_prop launch, occ 18->29% (AGPR-capped), 725us.
// R4: k_prop B-staging: 2-row loads + k-pair b32 writes, stride 40 + XOR
//     slot incl nn>>5, kin in-address -> 4-way max conflicts (was 8-way b16
//     scatter = 31% of cycles). k_e: 2 v/block, hoisted Mpp frag.
// ---------------------------------------------------------------------------

#define VDIM 400
#define VP   416            // v padded to multiple of 32
#define KV   (4*VP)         // 1664 : concat K dim over k=1..4
#define EROWS (5*VP)        // 2080 : e rows incl k=0
#define OL   2048           // 32 out-ch * 64 l
#define ALPHA_ 0.05f
#define BETA_  0.95f

typedef short  bf16x8 __attribute__((ext_vector_type(8)));
typedef float  f32x4  __attribute__((ext_vector_type(4)));

__device__ inline unsigned short f2bf(float x){
  unsigned int u = __float_as_uint(x);
  unsigned int r = (u + 0x7fffu + ((u >> 16) & 1u)) >> 16;
  return (unsigned short)r;
}
__device__ inline float bf2f(unsigned short u){
  return __uint_as_float(((unsigned int)u) << 16);
}

// ------------------------------------------------- edge MLP, fp32, R1 -------
__global__ __launch_bounds__(256) void k_mlp3(
    const float* __restrict__ adj,
    const float* __restrict__ w0, const float* __restrict__ b0,
    const float* __restrict__ w1, const float* __restrict__ b1,
    const float* __restrict__ w2, const float* __restrict__ b2,
    float* __restrict__ g)
{
  __shared__ __align__(16) float s_inT[64*68];   // [f][e], 17,408 B
  __shared__ __align__(16) float s_h1 [64*72];   // [e][n], 18,432 B
  __shared__ __align__(16) float s_red[4*64*2];  // 2,048 B
  const int tid  = threadIdx.x;
  const long ebase = (long)blockIdx.x * 64;
  const int wid  = __builtin_amdgcn_readfirstlane(tid >> 6);  // uniform wave id
  const int lane = tid & 63;                                  // = edge index

  // stage adj tile transposed: s_inT[f][e] = adj[ebase+e][f]
  #pragma unroll
  for (int i = 0; i < 4; ++i){
    const int idx = tid + i*256;
    const int row = idx >> 4, f4 = (idx & 15)*4;
    f32x4 v = *reinterpret_cast<const f32x4*>(&adj[(ebase + row)*64 + f4]);
    s_inT[(f4+0)*68 + row] = v.x;
    s_inT[(f4+1)*68 + row] = v.y;
    s_inT[(f4+2)*68 + row] = v.z;
    s_inT[(f4+3)*68 + row] = v.w;
  }
  __syncthreads();

  // ---- layer 0: h0[e = lane][n0 .. n0+31], n0 = wid*32 (K = 64)
  const int n0 = wid * 32;
  float h0[32];
  #pragma unroll
  for (int j = 0; j < 32; ++j) h0[j] = b0[n0 + j];           // uniform loads
  #pragma unroll 2
  for (int f = 0; f < 64; ++f){
    const float a = s_inT[f*68 + lane];                       // 1 ds_read_b32
    const float* __restrict__ wr = &w0[f*128 + n0];           // uniform -> SMEM
    #pragma unroll
    for (int j = 0; j < 32; ++j) h0[j] = fmaf(a, wr[j], h0[j]);
  }
  #pragma unroll
  for (int j = 0; j < 32; ++j) h0[j] = fmaxf(h0[j], 0.f);

  // ---- layer 1 partial: this wave's K-slice F = n0..n0+31, all 64 n-cols
  float p[64];
  #pragma unroll
  for (int nh = 0; nh < 2; ++nh){
    float acc1[32];
    #pragma unroll
    for (int j = 0; j < 32; ++j) acc1[j] = 0.f;
    #pragma unroll 2
    for (int f = 0; f < 32; ++f){
      const float hv = h0[f];
      const float* __restrict__ wr = &w1[(n0 + f)*64 + nh*32]; // uniform -> SMEM
      #pragma unroll
      for (int j = 0; j < 32; ++j) acc1[j] = fmaf(hv, wr[j], acc1[j]);
    }
    #pragma unroll
    for (int j = 0; j < 32; ++j) p[nh*32 + j] = acc1[j];
  }

  // ---- cross-wave accumulate into s_h1 (sequential phases, F-order 0..127)
  #pragma unroll
  for (int w = 0; w < 4; ++w){
    if (wid == w){
      if (w == 0){
        #pragma unroll
        for (int j = 0; j < 64; j += 4){
          f32x4 v = { p[j] + b1[j],   p[j+1] + b1[j+1],
                      p[j+2] + b1[j+2], p[j+3] + b1[j+3] };
          *reinterpret_cast<f32x4*>(&s_h1[lane*72 + j]) = v;
        }
      } else {
        #pragma unroll
        for (int j = 0; j < 64; j += 4){
          f32x4 v = *reinterpret_cast<f32x4*>(&s_h1[lane*72 + j]);
          v.x += p[j]; v.y += p[j+1]; v.z += p[j+2]; v.w += p[j+3];
          *reinterpret_cast<f32x4*>(&s_h1[lane*72 + j]) = v;
        }
      }
    }
    __syncthreads();
  }

  // ---- layer 2: g[e][gr] = relu(h1[e][:]) @ w2 + b2 ; wave handles 16 n's
  float q0 = 0.f, q1 = 0.f;
  #pragma unroll
  for (int j = 0; j < 16; ++j){
    const int n = wid*16 + j;
    const float hv = fmaxf(s_h1[lane*72 + n], 0.f);
    q0 = fmaf(hv, w2[n*2 + 0], q0);                           // uniform -> SMEM
    q1 = fmaf(hv, w2[n*2 + 1], q1);
  }
  s_red[(wid*64 + lane)*2 + 0] = q0;
  s_red[(wid*64 + lane)*2 + 1] = q1;
  __syncthreads();
  if (wid == 0){
    float r0 = b2[0], r1 = b2[1];
    #pragma unroll
    for (int w = 0; w < 4; ++w){
      r0 += s_red[(w*64 + lane)*2 + 0];
      r1 += s_red[(w*64 + lane)*2 + 1];
    }
    g[(ebase + lane)*2 + 0] = r0;
    g[(ebase + lane)*2 + 1] = r1;
  }
}

// ------------------------------------------- softmax + top-K + renorm + ^T --
// writes Bf[gr*2][w][v] = A_gr[v][w]   (1-hop transposed operator, fp32)
__global__ __launch_bounds__(256) void k_sparsify(
    const float* __restrict__ g, float* __restrict__ Bf)
{
  const int row = blockIdx.x, gr = blockIdx.y, tid = threadIdx.x;
  const int wid = tid >> 6, lane = tid & 63;
  __shared__ float s_v[4]; __shared__ int s_i[4];
  __shared__ float s_p[512];
  __shared__ int   s_sel[512];
  const int i0 = tid, i1 = tid + 256;
  float v0 = (i0 < VDIM) ? g[(row*VDIM + i0)*2 + gr] : -3.4e38f;
  float v1 = (i1 < VDIM) ? g[(row*VDIM + i1)*2 + gr] : -3.4e38f;

  float m = fmaxf(v0, v1);
  for (int off = 32; off > 0; off >>= 1) m = fmaxf(m, __shfl_down(m, off, 64));
  if (lane == 0) s_v[wid] = m;
  __syncthreads();
  const float rowmax = fmaxf(fmaxf(s_v[0], s_v[1]), fmaxf(s_v[2], s_v[3]));
  float p0 = (i0 < VDIM) ? expf(v0 - rowmax) : 0.f;
  float p1 = (i1 < VDIM) ? expf(v1 - rowmax) : 0.f;
  float zs = p0 + p1;
  for (int off = 32; off > 0; off >>= 1) zs += __shfl_down(zs, off, 64);
  __syncthreads();
  if (lane == 0) s_v[wid] = zs;
  __syncthreads();
  const float Z = s_v[0] + s_v[1] + s_v[2] + s_v[3];
  p0 /= Z; p1 /= Z;
  s_p[i0] = p0; s_p[i1] = p1;
  s_sel[i0] = (i0 < VDIM) ? 0 : 1;
  s_sel[i1] = (i1 < VDIM) ? 0 : 1;
  __syncthreads();

  float ssum = 0.f;
  for (int it = 0; it < 20; ++it){
    float cv = -1.f; int ci = 0x7fffffff;
    if (!s_sel[i0])              { cv = p0; ci = i0; }
    if (!s_sel[i1] && (p1 > cv)) { cv = p1; ci = i1; }
    for (int off = 32; off > 0; off >>= 1){
      float ov = __shfl_down(cv, off, 64); int oi = __shfl_down(ci, off, 64);
      if (ov > cv || (ov == cv && oi < ci)){ cv = ov; ci = oi; }
    }
    if (lane == 0){ s_v[wid] = cv; s_i[wid] = ci; }
    __syncthreads();
    float wv = s_v[0]; int wi_ = s_i[0];
    #pragma unroll
    for (int k = 1; k < 4; ++k){
      float ov = s_v[k]; int oi = s_i[k];
      if (ov > wv || (ov == wv && oi < wi_)){ wv = ov; wi_ = oi; }
    }
    ssum += wv;
    if (tid == (wi_ & 255)) s_sel[wi_] = 1;
    __syncthreads();
  }
  const float inv = 1.0f / (ssum + 1e-8f);
  float* B1 = Bf + (size_t)(gr*2) * (VDIM*VDIM);
  if (i0 < VDIM) B1[(size_t)i0*VDIM + row] = s_sel[i0] ? (s_p[i0]*inv) : 0.f;
  if (i1 < VDIM) B1[(size_t)i1*VDIM + row] = s_sel[i1] ? (s_p[i1]*inv) : 0.f;
}

// ------------------------------------------------ 2-hop: Bf[2g+1]=Bf[2g]^2 --
__global__ __launch_bounds__(256) void k_sq(float* __restrict__ Bf)
{
  const int gr = blockIdx.z;
  const float* S = Bf + (size_t)(2*gr)   * (VDIM*VDIM);
  float*       D = Bf + (size_t)(2*gr+1) * (VDIM*VDIM);
  const int tx = threadIdx.x & 15, ty = threadIdx.x >> 4;
  const int w = blockIdx.x*16 + ty, v = blockIdx.y*16 + tx;
  __shared__ float As[16][17], Bs[16][17];
  float acc = 0.f;
  for (int u0 = 0; u0 < VDIM; u0 += 16){
    As[ty][tx] = S[(size_t)w*VDIM + u0 + tx];
    Bs[ty][tx] = S[(size_t)(u0+ty)*VDIM + v];
    __syncthreads();
    #pragma unroll
    for (int u = 0; u < 16; ++u) acc += As[ty][u] * Bs[u][tx];
    __syncthreads();
  }
  D[(size_t)w*VDIM + v] = acc;
}

// ------------------- pack Bcat (bf16, padded) + build M'' + zero BN sums ---
__global__ __launch_bounds__(256) void k_pack(
    const float* __restrict__ Bf, const float* __restrict__ conv_w,
    unsigned short* __restrict__ Bcat, unsigned short* __restrict__ Mpp,
    float* __restrict__ bns)
{
  const int idx = blockIdx.x*256 + threadIdx.x;
  if (idx < 512*KV){
    const int w = idx / KV, col = idx % KV;
    const int k1 = col / VP, v = col % VP;
    float val = (w < VDIM && v < VDIM) ? Bf[(size_t)k1*(VDIM*VDIM) + (size_t)w*VDIM + v] : 0.f;
    Bcat[idx] = f2bf(val);
  }
  if (blockIdx.x == 0){
    const float a = ALPHA_, b = BETA_;
    for (int mIdx = threadIdx.x; mIdx < 160*32; mIdx += 256){
      const int rowm = mIdx >> 5, c = mIdx & 31;
      const int k = rowm / 32, o = rowm & 31;
      float W[5];
      #pragma unroll
      for (int j = 0; j < 5; ++j) W[j] = conv_w[o*160 + j*32 + c];
      float val;
      if      (k == 0) val = W[0] + a*(W[1]+W[2]+W[3]+W[4]);
      else if (k == 1) val = b*W[1] + a*b*W[2];
      else if (k == 2) val = b*b*W[2];
      else if (k == 3) val = b*W[3] + a*b*W[4];
      else             val = b*b*W[4];
      Mpp[rowm*32 + c] = f2bf(val);
    }
    if (threadIdx.x < 64) bns[threadIdx.x] = 0.f;
  }
}

// ----------------- e_k = M_k * relu(x), bf16, layout [n'][k*416+v][o*64+l] --
// R4: 2 v per block (grid 208 x NC), Mpp fragment hoisted.
__global__ __launch_bounds__(640) void k_e(
    const float* __restrict__ x, const unsigned short* __restrict__ Mpp,
    unsigned short* __restrict__ e, int n0)
{
  const int v0 = blockIdx.x * 2;
  const int n = n0 + blockIdx.y;
  const int tid = threadIdx.x;
  unsigned short* en = e + (size_t)blockIdx.y * EROWS * OL;
  if (v0 >= VDIM){
    // zero-fill both padded rows (v0, v0+1) for all 5 k planes
    for (int i = tid; i < 5*256*2; i += 640){
      const int row = i >> 8;                 // 0..9
      const int k = row >> 1, vv = row & 1;
      const int off = (i & 255) * 8;
      *reinterpret_cast<uint4*>(&en[(size_t)(k*VP + v0 + vv)*OL + off]) = make_uint4(0,0,0,0);
    }
    return;
  }
  __shared__ __align__(16) unsigned short s_xT[64*32];      // [l][c]
  __shared__ __align__(16) unsigned short s_out[10*16*64];  // per-wave [16][64]
  const int wid = tid >> 6, lane = tid & 63;
  const int l15 = lane & 15, q = lane >> 4;
  bf16x8 afrag = *reinterpret_cast<const bf16x8*>(&Mpp[(wid*16 + l15)*32 + q*8]);
  const f32x4 zero = {0.f, 0.f, 0.f, 0.f};

  #pragma unroll
  for (int vv = 0; vv < 2; ++vv){
    const int v = v0 + vv;
    if (vv) __syncthreads();     // all reads of s_xT (prev v) done
    if (tid < 512){
      const int c = tid >> 4, l4 = (tid & 15) * 4;
      float4 xv = *reinterpret_cast<const float4*>(x + ((size_t)n*32 + c)*25600 + (size_t)v*64 + l4);
      s_xT[(l4+0)*32 + c] = f2bf(fmaxf(xv.x, 0.f));
      s_xT[(l4+1)*32 + c] = f2bf(fmaxf(xv.y, 0.f));
      s_xT[(l4+2)*32 + c] = f2bf(fmaxf(xv.z, 0.f));
      s_xT[(l4+3)*32 + c] = f2bf(fmaxf(xv.w, 0.f));
    }
    __syncthreads();
    f32x4 acc[4];
    #pragma unroll
    for (int lt = 0; lt < 4; ++lt){
      bf16x8 bfrag = *reinterpret_cast<const bf16x8*>(&s_xT[(lt*16 + l15)*32 + q*8]);
      acc[lt] = __builtin_amdgcn_mfma_f32_16x16x32_bf16(afrag, bfrag, zero, 0, 0, 0);
    }
    unsigned short* so = &s_out[wid*1024];
    #pragma unroll
    for (int lt = 0; lt < 4; ++lt)
      #pragma unroll
      for (int r = 0; r < 4; ++r)
        so[(q*4 + r)*64 + lt*16 + l15] = f2bf(acc[lt][r]);
    const int k = wid >> 1, o0 = (wid & 1) * 16;
    const size_t gbase = (size_t)(k*VP + v)*OL + (size_t)o0*64;
    uint4 d0 = *reinterpret_cast<uint4*>(&so[lane*16]);
    uint4 d1 = *reinterpret_cast<uint4*>(&so[lane*16 + 8]);
    *reinterpret_cast<uint4*>(&en[gbase + lane*16])     = d0;
    *reinterpret_cast<uint4*>(&en[gbase + lane*16 + 8]) = d1;
  }
}

// ------- main GEMM: out[w][(o,l)] = Bcat[w][kv] @ e[kv][(o,l)] + e0 + bias --
// R4 staging: B loads 2 adjacent k-rows/thread (dwordx4), k-pair b32 writes
// into stride-40 rows with slot = kb ^ ((nn>>3)&3) ^ ((nn>>5)&3).
// Per-instruction banks = 20u + 4*slot + (r2&3) -> 16 distinct, 4-way max.
__global__ __launch_bounds__(256) void k_prop(
    const unsigned short* __restrict__ Bcat, const unsigned short* __restrict__ e,
    const float* __restrict__ conv_b, float* __restrict__ out,
    float* __restrict__ bns, int n0)
{
  const int mt = blockIdx.x, nt = blockIdx.y, np = blockIdx.z;
  const int tid = threadIdx.x;
  const int wid = tid >> 6, lane = tid & 63;
  const int l15 = lane & 15, q = lane >> 4;
  const int ww = wid & 1, wh = wid >> 1;
  const unsigned short* en = e + (size_t)np * EROWS * OL;
  __shared__ __align__(16) unsigned short s_a[128*40];  // [m][32k] pad 40
  __shared__ __align__(16) unsigned short s_b[128*40];  // [n][32k] pad 40, slotted
  const f32x4 zero = {0.f, 0.f, 0.f, 0.f};
  f32x4 acc[4][4];
  #pragma unroll
  for (int mi = 0; mi < 4; ++mi)
    #pragma unroll
    for (int ni = 0; ni < 4; ++ni) acc[mi][ni] = zero;
  const int w_base = mt*128, ol0 = nt*128;

  const int r2 = tid >> 4;     // 0..15 -> k-rows 2r2, 2r2+1
  const int sg = tid & 15;     // col oct
  const int kb = r2 >> 2;      // k-oct of this thread's rows
  const int kin2 = (2*r2) & 7; // even k within oct

  for (int kk = 0; kk < KV; kk += 32){
    // A: straight copy, 2x dwordx4 per thread
    #pragma unroll
    for (int i = 0; i < 2; ++i){
      const int idx = tid + i*256;
      const int m = idx >> 2, seg = idx & 3;
      uint4 d = *reinterpret_cast<const uint4*>(&Bcat[(size_t)(w_base + m)*KV + kk + seg*8]);
      *reinterpret_cast<uint4*>(&s_a[m*40 + seg*8]) = d;
    }
    // B: two adjacent k-rows, same col oct; pack k-pairs, 8x b32 writes
    {
      union { uint4 u; unsigned short s[8]; } d0, d1;
      d0.u = *reinterpret_cast<const uint4*>(&en[(size_t)(VP + kk + 2*r2    )*OL + ol0 + sg*8]);
      d1.u = *reinterpret_cast<const uint4*>(&en[(size_t)(VP + kk + 2*r2 + 1)*OL + ol0 + sg*8]);
      #pragma unroll
      for (int t = 0; t < 8; ++t){
        const int nn = sg*8 + t;
        const int slot = kb ^ ((nn >> 3) & 3) ^ ((nn >> 5) & 3);
        const unsigned int val = (unsigned int)d0.s[t] | ((unsigned int)d1.s[t] << 16);
        *reinterpret_cast<unsigned int*>(&s_b[nn*40 + slot*8 + kin2]) = val;
      }
    }
    __syncthreads();
    bf16x8 af[4], bfr[4];
    #pragma unroll
    for (int mi = 0; mi < 4; ++mi){
      const int m = ww*64 + mi*16 + l15;
      af[mi] = *reinterpret_cast<const bf16x8*>(&s_a[m*40 + q*8]);
    }
    #pragma unroll
    for (int ni = 0; ni < 4; ++ni){
      const int nn = wh*64 + ni*16 + l15;
      const int sl = q ^ ((nn >> 3) & 3) ^ ((nn >> 5) & 3);
      bfr[ni] = *reinterpret_cast<const bf16x8*>(&s_b[nn*40 + sl*8]);
    }
    #pragma unroll
    for (int mi = 0; mi < 4; ++mi)
      #pragma unroll
      for (int ni = 0; ni < 4; ++ni)
        acc[mi][ni] = __builtin_amdgcn_mfma_f32_16x16x32_bf16(af[mi], bfr[ni], acc[mi][ni], 0, 0, 0);
    __syncthreads();
  }

  const int n_g = n0 + np;
  const int o = (ol0 >> 6) + wh;          // each wave maps to exactly one out channel
  const float cb = conv_b[o];
  float bsum = 0.f, bsq = 0.f;
  #pragma unroll
  for (int mi = 0; mi < 4; ++mi){
    #pragma unroll
    for (int ni = 0; ni < 4; ++ni){
      const int nloc = wh*64 + ni*16 + l15;
      const int ol = ol0 + nloc;
      const int l = ol & 63;
      #pragma unroll
      for (int r = 0; r < 4; ++r){
        const int w = w_base + ww*64 + mi*16 + q*4 + r;
        if (w < VDIM){
          float val = acc[mi][ni][r] + bf2f(en[(size_t)w*OL + ol]) + cb;
          out[(((size_t)n_g*32 + o)*VDIM + w)*64 + l] = val;
          bsum += val; bsq += val*val;
        }
      }
    }
  }
  for (int off = 32; off > 0; off >>= 1){
    bsum += __shfl_down(bsum, off, 64);
    bsq  += __shfl_down(bsq,  off, 64);
  }
  if (lane == 0){
    atomicAdd(&bns[o], bsum);
    atomicAdd(&bns[32 + o], bsq);
  }
}

// --------------------------------------------------- batchnorm (in-place) --
__global__ __launch_bounds__(256) void k_bnapply(
    float* __restrict__ out, const float* __restrict__ bns,
    const float* __restrict__ gamma, const float* __restrict__ beta, int total4)
{
  const int idx = blockIdx.x*256 + threadIdx.x;
  if (idx >= total4) return;
  const int o = (int)(((long)idx*4 / 25600) & 31);
  const float invM = 1.f / 819200.f;
  const float mean = bns[o] * invM;
  const float var  = bns[32+o] * invM - mean*mean;
  const float inv  = 1.0f / sqrtf(var + 1e-5f);
  const float sc = inv * gamma[o];
  const float sh = beta[o] - mean * sc;
  float4 v = reinterpret_cast<float4*>(out)[idx];
  v.x = v.x*sc + sh; v.y = v.y*sc + sh; v.z = v.z*sc + sh; v.w = v.w*sc + sh;
  reinterpret_cast<float4*>(out)[idx] = v;
}

// ---------------------------------------------------------------------------
extern "C" void kernel_launch(void* const* d_in, const int* in_sizes, int n_in,
                              void* d_out, int out_size, void* d_ws, size_t ws_size,
                              hipStream_t stream)
{
  const float* x      = (const float*)d_in[0];
  const float* adj    = (const float*)d_in[1];
  const float* w0     = (const float*)d_in[2];
  const float* b0     = (const float*)d_in[3];
  const float* w1     = (const float*)d_in[4];
  const float* b1     = (const float*)d_in[5];
  const float* w2     = (const float*)d_in[6];
  const float* b2     = (const float*)d_in[7];
  const float* conv_w = (const float*)d_in[8];
  const float* conv_b = (const float*)d_in[9];
  const float* gamma  = (const float*)d_in[10];
  const float* beta   = (const float*)d_in[11];
  float* out = (float*)d_out;

  char* ws = (char*)d_ws;
  size_t off = 0;
  auto alloc = [&](size_t bytes) -> void* {
    void* p = ws + off;
    off = (off + bytes + 255) & ~(size_t)255;
    return p;
  };
  float*          g_   = (float*)         alloc((size_t)VDIM*VDIM*2*4);
  float*          Bf   = (float*)         alloc((size_t)4*VDIM*VDIM*4);
  unsigned short* Bcat = (unsigned short*)alloc((size_t)512*KV*2);
  unsigned short* Mpp  = (unsigned short*)alloc((size_t)160*32*2);
  float*          bns  = (float*)         alloc((size_t)64*4);
  const size_t per_n = (size_t)EROWS * OL * 2;
  size_t avail = (ws_size > off) ? (ws_size - off) : 0;
  int NC = (int)(avail / per_n);
  if (NC > 32) NC = 32;           // one k_prop launch when ws allows
  if (NC < 1) NC = 1;
  while (32 % NC) NC--;
  unsigned short* ebuf = (unsigned short*)(ws + off);

  k_mlp3<<<2500, 256, 0, stream>>>(adj, w0, b0, w1, b1, w2, b2, g_);
  k_sparsify<<<dim3(VDIM, 2), 256, 0, stream>>>(g_, Bf);
  k_sq<<<dim3(25, 25, 2), 256, 0, stream>>>(Bf);
  k_pack<<<(512*KV + 255)/256, 256, 0, stream>>>(Bf, conv_w, Bcat, Mpp, bns);
  for (int n0 = 0; n0 < 32; n0 += NC){
    k_e<<<dim3(VP/2, NC), 640, 0, stream>>>(x, Mpp, ebuf, n0);
    k_prop<<<dim3(4, 16, NC), 256, 0, stream>>>(Bcat, ebuf, conv_b, out, bns, n0);
  }
  k_bnapply<<<(26214400/4 + 255)/256, 256, 0, stream>>>(out, bns, gamma, beta, 26214400/4);
}